// Round 5
// baseline (371.365 us; speedup 1.0000x reference)
//
#include <hip/hip_runtime.h>

// ChebyKANLayer: y[t,o] = bias[o] + sum_k A[t,k]*B[k,o], K=8192, k=i*8+(d-1), d=1..8.
// R11: kill the LDS-BW wall (R10 post-mortem: 1920cy LDS vs 1032cy MFMA per step).
// A-fragments are REGENERATED in registers (R6-verified Chebyshev chain) from tanh
// seeds staged through the LDS ring; only B (+8KB seeds) flows through LDS.
// R10's single-barrier counted-vmcnt ring pipeline retained. No A materialization.

typedef __bf16 bf16;
typedef __bf16 bf16x8 __attribute__((ext_vector_type(8)));
typedef float f32x2 __attribute__((ext_vector_type(2)));
typedef float f32x4 __attribute__((ext_vector_type(4)));
typedef float f32x16 __attribute__((ext_vector_type(16)));

#define MFMA __builtin_amdgcn_mfma_f32_32x32x16_bf16

__device__ __forceinline__ void g2lds16(const void* g, void* l) {
  __builtin_amdgcn_global_load_lds(
      (const __attribute__((address_space(1))) unsigned int*)g,
      (__attribute__((address_space(3))) unsigned int*)l, 16, 0, 0);
}

__device__ __forceinline__ float fast_tanh(float a) {
  float e = __expf(a + a);
  return 1.f - 2.f * __builtin_amdgcn_rcpf(e + 1.f);   // saturating, NaN-free
}

// ============================ PREP ============================
// th2[r][t*8 + pos] = tanh(x[r][8t+li]), pos = (li&1)*4 + (li>>1)  (even i's then odd i's
// within each 8-group) -> one b128 read in gemm = 4 seeds for ks=0..3 at parity h.
// B global layout (verified R9/R10): [nb 0..7][kt 0..127][8192 bf16], elem
// (((ks*4+n32)*2+h)*32+o31)*8 + (d-1), with i = kt*8 + 2ks + h.
// bias_p[p][o] = sum_{i in 32-block p} C[i][o][0].
__global__ __launch_bounds__(256)
void cheby_prep5(const float* __restrict__ x, const float* __restrict__ C,
                 bf16* __restrict__ B, float* __restrict__ bias_p,
                 float* __restrict__ th2) {
  const int bid = blockIdx.x, tid = threadIdx.x;
  if (bid < 4096) {                                  // ---- th2-gen: 8 i per thread
    const int g = bid * 256 + tid;                   // 1M groups
    const int r = g >> 7, i0 = (g & 127) * 8;
    const float* xp = x + (size_t)r * 1024 + i0;
    f32x4 v0 = *(const f32x4*)(xp);
    f32x4 v1 = *(const f32x4*)(xp + 4);
    f32x4 e, o;
    e.x = fast_tanh(v0.x); e.y = fast_tanh(v0.z); e.z = fast_tanh(v1.x); e.w = fast_tanh(v1.z);
    o.x = fast_tanh(v0.y); o.y = fast_tanh(v0.w); o.z = fast_tanh(v1.y); o.w = fast_tanh(v1.w);
    float* dp = th2 + (size_t)r * 1024 + i0;
    *(f32x4*)(dp)     = e;                           // pos 0..3: li = 0,2,4,6
    *(f32x4*)(dp + 4) = o;                           // pos 4..7: li = 1,3,5,7
    return;
  }
  // ---- B repack + bias partials: 32 i x 32 o per block (1024 blocks)
  const int b2 = bid - 4096;
  __shared__ float tile[32][292];
  const int i0 = (b2 >> 5) * 32, o0 = (b2 & 31) * 32;
  {
    const int r = tid >> 3, seg = tid & 7;
    const float* src = C + (size_t)(i0 + r) * 9216 + (size_t)o0 * 9 + seg * 36;
    float* dst = &tile[r][seg * 36];
    #pragma unroll
    for (int v = 0; v < 9; ++v) *(f32x4*)(dst + v * 4) = *(const f32x4*)(src + v * 4);
  }
  __syncthreads();
  #pragma unroll
  for (int j = 0; j < 4; ++j) {
    int e = tid + 256 * j;
    int il = e >> 5, ol = e & 31;
    int i = i0 + il, o = o0 + ol;
    bf16x8 v;
    #pragma unroll
    for (int d = 0; d < 8; ++d) v[d] = (bf16)tile[il][ol * 9 + 1 + d];
    const int cc = i & 7;
    size_t tnum = (size_t)(o >> 7) * 128 + (i >> 3);
    const int widx = (((cc >> 1) * 4 + ((o & 127) >> 5)) * 2 + (cc & 1)) * 32 + (o & 31);
    *(bf16x8*)(B + tnum * 8192 + widx * 8) = v;
  }
  if (tid < 32) {
    float s = 0.f;
    #pragma unroll
    for (int i = 0; i < 32; ++i) s += tile[i][tid * 9];
    bias_p[(size_t)(b2 >> 5) * 1024 + o0 + tid] = s;
  }
}

// ============================ GEMM (A gen-in-reg + B/seed LDS ring) ============================
// Block 256x128, 512 thr, 8 waves (4M x 2N), wave tile 64x64, BK=64, 128 K-steps.
// Ring[3] bufs of 24KB: [0,8192) B tile image (bf16), [8192,12288) th seeds (2048 f32).
// 3 g2lds/step (B x2 + th x1). Step t: issue batch(t+3); ds_read B-frags(t+1) + seeds(t+1);
// gen A-frags(t+1) (VALU, overlaps MFMA); MFMA(t); lgkmcnt(0); vmcnt(3); barrier.
__global__ __launch_bounds__(512, 1)
void cheby_gemm6(const float* __restrict__ th2, const bf16* __restrict__ B,
                 const float* __restrict__ bias_p, float* __restrict__ out) {
  __shared__ bf16 ring[3][12288];                    // 3 x 24 KB = 72 KB
  const int tid = threadIdx.x;
  const int lane = tid & 63, w = tid >> 6;
  const int wm = w >> 1, wn = w & 1;
  const int bid = blockIdx.x;
  const int wgid = (bid & 7) * 32 + (bid >> 3);      // XCD-chunked, bijective (256 = 8*32)
  const int mb2 = wgid >> 3, nb = wgid & 7;

  const int ml = lane & 31, h = lane >> 5;
  const int bBase = wn * 1024 + h * 256 + ml * 8;    // + ks*2048, + nt*512
  const int row0 = wm * 64;                          // wave's first local row
  const int sIdx = (row0 + ml) * 8 + h * 4;          // f32 idx into th region; +256 for row+32

  const bf16*  bG = B   + (size_t)nb * 1048576 + tid * 8;
  const float* tG = th2 + (size_t)(mb2 * 256 + (tid >> 1)) * 1024 + (tid & 1) * 4;

  f32x16 acc[2][2];
  #pragma unroll
  for (int a = 0; a < 2; ++a)
    #pragma unroll
    for (int b = 0; b < 2; ++b)
      #pragma unroll
      for (int r = 0; r < 16; ++r) acc[a][b][r] = 0.f;

  bf16x8 afr0[2][4], afr1[2][4];                     // A frags [mt][ks] (gen'd)
  bf16x8 bfr0[2][4], bfr1[2][4];                     // B frags [nt][ks]

  auto issue3 = [&](int t, int p) {
    g2lds16(bG + (size_t)t * 8192,        &ring[p][tid * 8]);
    g2lds16(bG + (size_t)t * 8192 + 4096, &ring[p][4096 + tid * 8]);
    g2lds16(tG + (size_t)t * 8,           &ring[p][8192 + tid * 8]);
  };
  auto loadBF = [&](bf16x8 (&bf)[2][4], const bf16* ra) {
    #pragma unroll
    for (int ks = 0; ks < 4; ++ks) {
      bf[0][ks] = *(const bf16x8*)(ra + bBase + ks * 2048);
      bf[1][ks] = *(const bf16x8*)(ra + bBase + ks * 2048 + 512);
    }
  };
  // R6-verified Chebyshev chain: dst[mt][ks][j] = T_{j+1}(tanh(x[row, 8t+2ks+h]))
  auto gen = [&](bf16x8 (&dst)[2][4], const bf16* ra) {
    const float* thL = (const float*)(ra + 8192);
    f32x4 s0 = *(const f32x4*)(thL + sIdx);          // rows row0+ml
    f32x4 s1 = *(const f32x4*)(thL + sIdx + 256);    // rows row0+32+ml
    #pragma unroll
    for (int ks = 0; ks < 4; ++ks) {
      f32x2 t  = {s0[ks], s1[ks]};
      f32x2 t2 = t + t;
      f32x2 prev = {1.f, 1.f}, cur = t;
      #pragma unroll
      for (int j = 0; j < 8; ++j) {
        dst[0][ks][j] = (bf16)cur.x;
        dst[1][ks][j] = (bf16)cur.y;
        f32x2 nx = t2 * cur - prev;
        prev = cur; cur = nx;
      }
    }
  };
  auto mfma16 = [&](bf16x8 (&af)[2][4], bf16x8 (&bf)[2][4]) {
    __builtin_amdgcn_s_setprio(1);
    #pragma unroll
    for (int ks = 0; ks < 4; ++ks) {
      acc[0][0] = MFMA(af[0][ks], bf[0][ks], acc[0][0], 0, 0, 0);
      acc[0][1] = MFMA(af[0][ks], bf[1][ks], acc[0][1], 0, 0, 0);
      acc[1][0] = MFMA(af[1][ks], bf[0][ks], acc[1][0], 0, 0, 0);
      acc[1][1] = MFMA(af[1][ks], bf[1][ks], acc[1][1], 0, 0, 0);
    }
    __builtin_amdgcn_s_setprio(0);
  };

  // prologue: batches 0,1,2 -> bufs 0,1,2; tile0 landed at vmcnt(6); frags(0) -> set 0
  issue3(0, 0); issue3(1, 1); issue3(2, 2);
  asm volatile("s_waitcnt vmcnt(6)" ::: "memory");
  __builtin_amdgcn_s_barrier();
  loadBF(bfr0, &ring[0][0]);
  gen(afr0, &ring[0][0]);
  asm volatile("s_waitcnt lgkmcnt(0)" ::: "memory"); // all waves' tile-0 reads done
  __builtin_amdgcn_s_barrier();                      // -> buf0 overwritable

  auto step = [&](int t, int pI, int pR,
                  bf16x8 (&curA)[2][4], bf16x8 (&curB)[2][4],
                  bf16x8 (&nxtA)[2][4], bf16x8 (&nxtB)[2][4], bool rd) {
    if (t + 3 < 128) issue3(t + 3, pI);              // pI = t%3 (dead since end of t-1)
    if (rd) {
      loadBF(nxtB, &ring[pR][0]);                    // pR = (t+1)%3
      gen(nxtA, &ring[pR][0]);                       // VALU fills MFMA shadow
    }
    mfma16(curA, curB);
    asm volatile("s_waitcnt lgkmcnt(0)" ::: "memory");
    if (t < 125) asm volatile("s_waitcnt vmcnt(3)" ::: "memory");  // batch(t+2) landed
    else         asm volatile("s_waitcnt vmcnt(0)" ::: "memory");
    __builtin_amdgcn_s_barrier();
  };

  #pragma unroll 1
  for (int t6 = 0; t6 < 126; t6 += 6) {              // static ring/parity: lcm(3,2)=6
    step(t6 + 0, 0, 1, afr0, bfr0, afr1, bfr1, true);
    step(t6 + 1, 1, 2, afr1, bfr1, afr0, bfr0, true);
    step(t6 + 2, 2, 0, afr0, bfr0, afr1, bfr1, true);
    step(t6 + 3, 0, 1, afr1, bfr1, afr0, bfr0, true);
    step(t6 + 4, 1, 2, afr0, bfr0, afr1, bfr1, true);
    step(t6 + 5, 2, 0, afr1, bfr1, afr0, bfr0, true);
  }
  step(126, 0, 1, afr0, bfr0, afr1, bfr1, true);
  step(127, 1, 2, afr1, bfr1, afr0, bfr0, false);

  // epilogue: C/D layout col=lane&31, row=(r&3)+8*(r>>2)+4*h (verified)
  const int c0 = nb * 128 + wn * 64 + ml;
  float bv0 = 0.f, bv1 = 0.f;
  #pragma unroll
  for (int p = 0; p < 32; ++p) {
    bv0 += bias_p[(size_t)p * 1024 + c0];
    bv1 += bias_p[(size_t)p * 1024 + c0 + 32];
  }
  const int r0 = mb2 * 256 + wm * 64;
  #pragma unroll
  for (int mt = 0; mt < 2; ++mt)
    #pragma unroll
    for (int r = 0; r < 16; ++r) {
      int row = r0 + mt * 32 + (r & 3) + 8 * (r >> 2) + 4 * h;
      float* po = out + (size_t)row * 1024 + c0;
      po[0]  = acc[mt][0][r] + bv0;
      po[32] = acc[mt][1][r] + bv1;
    }
}

// ---- naive fallback (ws too small) — correct, slow, should never run
__global__ __launch_bounds__(256)
void cheby_naive(const float* __restrict__ x, const float* __restrict__ C,
                 float* __restrict__ out) {
  const int t = blockIdx.x, tid = threadIdx.x;
  float acc[4] = {0.f, 0.f, 0.f, 0.f};
  for (int i = 0; i < 1024; ++i) {
    float th = tanhf(x[(size_t)t * 1024 + i]);
    float T[9]; T[0] = 1.f; T[1] = th;
    #pragma unroll
    for (int d = 2; d < 9; ++d) T[d] = 2.f * th * T[d - 1] - T[d - 2];
    #pragma unroll
    for (int j = 0; j < 4; ++j) {
      const float* cp = &C[((size_t)i * 1024 + tid + j * 256) * 9];
      float s = 0.f;
      #pragma unroll
      for (int d = 0; d < 9; ++d) s += T[d] * cp[d];
      acc[j] += s;
    }
  }
  #pragma unroll
  for (int j = 0; j < 4; ++j) out[(size_t)t * 1024 + tid + j * 256] = acc[j];
}

extern "C" void kernel_launch(void* const* d_in, const int* in_sizes, int n_in,
                              void* d_out, int out_size, void* d_ws, size_t ws_size,
                              hipStream_t stream) {
  (void)in_sizes; (void)n_in; (void)out_size;
  const float* x = (const float*)d_in[0];
  const float* C = (const float*)d_in[1];
  float* out = (float*)d_out;

  const size_t b_bytes  = (size_t)8 * 128 * 8192 * 2;     // 16.78 MB
  const size_t bp_bytes = (size_t)32 * 1024 * 4;          // 128 KB
  const size_t th_bytes = (size_t)8192 * 1024 * 4;        // 33.55 MB

  if (ws_size >= b_bytes + bp_bytes + th_bytes) {
    bf16*  B      = (bf16*)d_ws;
    float* bias_p = (float*)((char*)d_ws + b_bytes);
    float* th2    = (float*)((char*)d_ws + b_bytes + bp_bytes);
    cheby_prep5<<<5120, 256, 0, stream>>>(x, C, B, bias_p, th2);
    cheby_gemm6<<<256, 512, 0, stream>>>(th2, B, bias_p, out);
  } else {
    cheby_naive<<<8192, 256, 0, stream>>>(x, C, out);
  }
}

// Round 6
// 245.111 us; speedup vs baseline: 1.5151x; 1.5151x over previous
//
#include <hip/hip_runtime.h>

// ChebyKANLayer: y[t,o] = bias[o] + sum_k A[t,k]*B[k,o], K=8192, k=i*8+(d-1), d=1..8.
// R12 = R11 (gen-A-in-registers, verified correct) minus its two measured defects:
//  (1) spill (434MB scratch writebacks): frags now single-buffered + step-local,
//      __launch_bounds__(512,2); prefetch distance 2 on the 3-deep ring.
//  (2) seed-read 8-way bank conflict: th2 stored pos-major [mb][kt][pos][row] ->
//      seed reads are lane-consecutive b32, conflict-free.
// B image, fragment layouts, gen chain, epilogue: byte-identical to verified kernels.

typedef __bf16 bf16;
typedef __bf16 bf16x8 __attribute__((ext_vector_type(8)));
typedef float f32x2 __attribute__((ext_vector_type(2)));
typedef float f32x4 __attribute__((ext_vector_type(4)));
typedef float f32x16 __attribute__((ext_vector_type(16)));

#define MFMA __builtin_amdgcn_mfma_f32_32x32x16_bf16

__device__ __forceinline__ void g2lds16(const void* g, void* l) {
  __builtin_amdgcn_global_load_lds(
      (const __attribute__((address_space(1))) unsigned int*)g,
      (__attribute__((address_space(3))) unsigned int*)l, 16, 0, 0);
}

__device__ __forceinline__ float fast_tanh(float a) {
  float e = __expf(a + a);
  return 1.f - 2.f * __builtin_amdgcn_rcpf(e + 1.f);   // saturating, NaN-free
}

// ============================ PREP ============================
// th2 global layout (POS-MAJOR): float th2[32][128][8][256]:
//   th2[mb][kt][pos][row] = tanh(x[mb*256+row][kt*8+li]), li = (pos>>2) + 2*(pos&3)
//   (equivalently pos = (li&1)*4 + (li>>1); i = kt*8 + 2*ks + h with pos = h*4 + ks).
// B global layout (verified): [nb 0..7][kt 0..127][8192 bf16], elem
//   (((ks*4+n32)*2+h)*32+o31)*8 + (d-1).
// bias_p[p][o] = sum_{i in 32-block p} C[i][o][0].
__global__ __launch_bounds__(256)
void cheby_prep6(const float* __restrict__ x, const float* __restrict__ C,
                 bf16* __restrict__ B, float* __restrict__ bias_p,
                 float* __restrict__ th2) {
  const int bid = blockIdx.x, tid = threadIdx.x;
  if (bid < 1024) {                                  // ---- th2-gen: 64 rows x 128 i
    __shared__ float xs[64][129];                    // pad -> LDS reads 2-way (free)
    const int r0 = (bid >> 3) * 64, c0 = (bid & 7) * 128;
    #pragma unroll
    for (int it = 0; it < 8; ++it) {                 // coalesced x stage: 64x128 f32
      const int e = tid + it * 256;
      const int rr = e >> 5, c4 = (e & 31) * 4;
      f32x4 v = *(const f32x4*)(x + (size_t)(r0 + rr) * 1024 + c0 + c4);
      xs[rr][c4 + 0] = v.x; xs[rr][c4 + 1] = v.y;
      xs[rr][c4 + 2] = v.z; xs[rr][c4 + 3] = v.w;
    }
    __syncthreads();
    const int row = tid & 63, kq = tid >> 6;         // wave kq owns 4 local kt
    const int mb = r0 >> 8, rowp = (r0 & 255) + row;
    const int kt0 = c0 >> 3;                         // global kt base (16 per block)
    float* outp = th2 + (size_t)mb * 128 * 2048;
    #pragma unroll
    for (int kk = 0; kk < 4; ++kk) {
      const int kt = kq * 4 + kk;                    // local kt 0..15
      #pragma unroll
      for (int li = 0; li < 8; ++li) {
        float z = fast_tanh(xs[row][kt * 8 + li]);
        const int pos = (li & 1) * 4 + (li >> 1);
        outp[((size_t)(kt0 + kt) * 8 + pos) * 256 + rowp] = z;  // 256B/wave contiguous
      }
    }
    return;
  }
  // ---- B repack + bias partials: 32 i x 32 o per block (1024 blocks, verified)
  const int b2 = bid - 1024;
  __shared__ float tile[32][292];
  const int i0 = (b2 >> 5) * 32, o0 = (b2 & 31) * 32;
  {
    const int r = tid >> 3, seg = tid & 7;
    const float* src = C + (size_t)(i0 + r) * 9216 + (size_t)o0 * 9 + seg * 36;
    float* dst = &tile[r][seg * 36];
    #pragma unroll
    for (int v = 0; v < 9; ++v) *(f32x4*)(dst + v * 4) = *(const f32x4*)(src + v * 4);
  }
  __syncthreads();
  #pragma unroll
  for (int j = 0; j < 4; ++j) {
    int e = tid + 256 * j;
    int il = e >> 5, ol = e & 31;
    int i = i0 + il, o = o0 + ol;
    bf16x8 v;
    #pragma unroll
    for (int d = 0; d < 8; ++d) v[d] = (bf16)tile[il][ol * 9 + 1 + d];
    const int cc = i & 7;
    size_t tnum = (size_t)(o >> 7) * 128 + (i >> 3);
    const int widx = (((cc >> 1) * 4 + ((o & 127) >> 5)) * 2 + (cc & 1)) * 32 + (o & 31);
    *(bf16x8*)(B + tnum * 8192 + widx * 8) = v;
  }
  if (tid < 32) {
    float s = 0.f;
    #pragma unroll
    for (int i = 0; i < 32; ++i) s += tile[i][tid * 9];
    bias_p[(size_t)(b2 >> 5) * 1024 + o0 + tid] = s;
  }
}

// ============================ GEMM (gen-A-in-reg, single-buffered frags) ============================
// Block 256x128, 512 thr, 8 waves (4M x 2N), wave tile 64x64, BK=64, 128 K-steps.
// Ring[3] bufs of 24KB: [0,8192) B tile image (bf16), [8192,12288) seeds (2048 f32,
// pos-major [pos][row]). 3 g2lds/step, prefetch distance 2, one vmcnt+barrier per step.
__global__ __launch_bounds__(512, 2)
void cheby_gemm7(const float* __restrict__ th2, const bf16* __restrict__ B,
                 const float* __restrict__ bias_p, float* __restrict__ out) {
  __shared__ bf16 ring[3][12288];                    // 3 x 24 KB = 72 KB
  const int tid = threadIdx.x;
  const int lane = tid & 63, w = tid >> 6;
  const int wm = w >> 1, wn = w & 1;
  const int bid = blockIdx.x;
  const int wgid = (bid & 7) * 32 + (bid >> 3);      // XCD-chunked, bijective (256 = 8*32)
  const int mb2 = wgid >> 3, nb = wgid & 7;

  const int ml = lane & 31, h = lane >> 5;
  const int bBase = wn * 1024 + h * 256 + ml * 8;    // + ks*2048, + nt*512
  const int row0 = wm * 64;
  const int sOff = h * 1024 + row0 + ml;             // f32 idx: (h*4+ks)*256 + row; +32 row1

  const bf16*  bG = B   + (size_t)nb * 1048576 + tid * 8;
  const float* tG = th2 + (size_t)mb2 * 262144 + tid * 4;     // 128 kt * 2048 f32

  f32x16 acc[2][2];
  #pragma unroll
  for (int a = 0; a < 2; ++a)
    #pragma unroll
    for (int b = 0; b < 2; ++b)
      #pragma unroll
      for (int r = 0; r < 16; ++r) acc[a][b][r] = 0.f;

  auto issue3 = [&](int t, int p) {
    g2lds16(bG + (size_t)t * 8192,        &ring[p][tid * 8]);
    g2lds16(bG + (size_t)t * 8192 + 4096, &ring[p][4096 + tid * 8]);
    g2lds16(tG + (size_t)t * 2048,        &ring[p][8192 + tid * 8]);  // 8KB seeds
  };

  // prologue: tiles 0,1 -> bufs 0,1; own batch-0 done; barrier -> tile 0 fully landed
  issue3(0, 0); issue3(1, 1);
  asm volatile("s_waitcnt vmcnt(3)" ::: "memory");
  __builtin_amdgcn_s_barrier();

  auto step = [&](int t, int pC, int pN) {
    if (t + 2 < 128) issue3(t + 2, pN);              // pN=(t+2)%3: dead since end of t-1
    const bf16* ra = &ring[pC][0];
    const float* seedL = (const float*)(ra + 8192);
    bf16x8 bfr[2][4], afr[2][4];                     // step-local: no cross-step liveness
    #pragma unroll
    for (int ks = 0; ks < 4; ++ks) {
      bfr[0][ks] = *(const bf16x8*)(ra + bBase + ks * 2048);
      bfr[1][ks] = *(const bf16x8*)(ra + bBase + ks * 2048 + 512);
    }
    #pragma unroll
    for (int ks = 0; ks < 4; ++ks) {                 // verified Chebyshev chain
      f32x2 tv = { seedL[sOff + ks * 256], seedL[sOff + ks * 256 + 32] };
      f32x2 t2 = tv + tv;
      f32x2 prev = {1.f, 1.f}, cur = tv;
      #pragma unroll
      for (int j = 0; j < 8; ++j) {
        afr[0][ks][j] = (bf16)cur.x;
        afr[1][ks][j] = (bf16)cur.y;
        f32x2 nx = t2 * cur - prev;
        prev = cur; cur = nx;
      }
    }
    __builtin_amdgcn_s_setprio(1);
    #pragma unroll
    for (int ks = 0; ks < 4; ++ks) {
      acc[0][0] = MFMA(afr[0][ks], bfr[0][ks], acc[0][0], 0, 0, 0);
      acc[0][1] = MFMA(afr[0][ks], bfr[1][ks], acc[0][1], 0, 0, 0);
      acc[1][0] = MFMA(afr[1][ks], bfr[0][ks], acc[1][0], 0, 0, 0);
      acc[1][1] = MFMA(afr[1][ks], bfr[1][ks], acc[1][1], 0, 0, 0);
    }
    __builtin_amdgcn_s_setprio(0);
    asm volatile("s_waitcnt lgkmcnt(0)" ::: "memory");   // pC reads done before barrier
    if (t <= 125) asm volatile("s_waitcnt vmcnt(3)" ::: "memory");  // batch(t+1) landed
    else          asm volatile("s_waitcnt vmcnt(0)" ::: "memory");
    __builtin_amdgcn_s_barrier();
  };

  #pragma unroll 1
  for (int t3 = 0; t3 < 126; t3 += 3) {              // static ring indices
    step(t3,     0, 2);
    step(t3 + 1, 1, 0);
    step(t3 + 2, 2, 1);
  }
  step(126, 0, 2);                                   // no issue (t+2 >= 128)
  step(127, 1, 0);                                   // no issue

  // epilogue: C/D layout col=lane&31, row=(r&3)+8*(r>>2)+4*h (verified)
  const int c0 = nb * 128 + wn * 64 + ml;
  float bv0 = 0.f, bv1 = 0.f;
  #pragma unroll
  for (int p = 0; p < 32; ++p) {
    bv0 += bias_p[(size_t)p * 1024 + c0];
    bv1 += bias_p[(size_t)p * 1024 + c0 + 32];
  }
  const int r0 = mb2 * 256 + wm * 64;
  #pragma unroll
  for (int mt = 0; mt < 2; ++mt)
    #pragma unroll
    for (int r = 0; r < 16; ++r) {
      int row = r0 + mt * 32 + (r & 3) + 8 * (r >> 2) + 4 * h;
      float* po = out + (size_t)row * 1024 + c0;
      po[0]  = acc[mt][0][r] + bv0;
      po[32] = acc[mt][1][r] + bv1;
    }
}

// ---- naive fallback (ws too small) — correct, slow, should never run
__global__ __launch_bounds__(256)
void cheby_naive(const float* __restrict__ x, const float* __restrict__ C,
                 float* __restrict__ out) {
  const int t = blockIdx.x, tid = threadIdx.x;
  float acc[4] = {0.f, 0.f, 0.f, 0.f};
  for (int i = 0; i < 1024; ++i) {
    float th = tanhf(x[(size_t)t * 1024 + i]);
    float T[9]; T[0] = 1.f; T[1] = th;
    #pragma unroll
    for (int d = 2; d < 9; ++d) T[d] = 2.f * th * T[d - 1] - T[d - 2];
    #pragma unroll
    for (int j = 0; j < 4; ++j) {
      const float* cp = &C[((size_t)i * 1024 + tid + j * 256) * 9];
      float s = 0.f;
      #pragma unroll
      for (int d = 0; d < 9; ++d) s += T[d] * cp[d];
      acc[j] += s;
    }
  }
  #pragma unroll
  for (int j = 0; j < 4; ++j) out[(size_t)t * 1024 + tid + j * 256] = acc[j];
}

extern "C" void kernel_launch(void* const* d_in, const int* in_sizes, int n_in,
                              void* d_out, int out_size, void* d_ws, size_t ws_size,
                              hipStream_t stream) {
  (void)in_sizes; (void)n_in; (void)out_size;
  const float* x = (const float*)d_in[0];
  const float* C = (const float*)d_in[1];
  float* out = (float*)d_out;

  const size_t b_bytes  = (size_t)8 * 128 * 8192 * 2;     // 16.78 MB
  const size_t bp_bytes = (size_t)32 * 1024 * 4;          // 128 KB
  const size_t th_bytes = (size_t)32 * 128 * 8 * 256 * 4; // 33.55 MB

  if (ws_size >= b_bytes + bp_bytes + th_bytes) {
    bf16*  B      = (bf16*)d_ws;
    float* bias_p = (float*)((char*)d_ws + b_bytes);
    float* th2    = (float*)((char*)d_ws + b_bytes + bp_bytes);
    cheby_prep6<<<2048, 256, 0, stream>>>(x, C, B, bias_p, th2);
    cheby_gemm7<<<256, 512, 0, stream>>>(th2, B, bias_p, out);
  } else {
    cheby_naive<<<8192, 256, 0, stream>>>(x, C, out);
  }
}